// Round 1
// baseline (151.695 us; speedup 1.0000x reference)
//
#include <hip/hip_runtime.h>

// BSHConv3D fused kernel.
// dims: B=1, D=H=W=48, C=8, K=3, R=2, NH=16, OUT=16.
// out: [48,48,48,16(f),16(n),2(re/im)] fp32, 226 MB.
//
// Block = 512 threads = 8 waves; each wave computes one voxel (strip of 8 along W).
// Grid = 48*48*6 blocks.

#define NBLK (48*48*6)

__global__ __launch_bounds__(512) void bsh_kernel(
    const float* __restrict__ X,   // [48,48,48,8]
    const float* __restrict__ AR,  // [27,2,16]
    const float* __restrict__ AI,  // [27,2,16]
    const float* __restrict__ Wgt, // [8,16,2,4]
    const float* __restrict__ WC,  // [8,16]
    const float* __restrict__ Bc,  // [16]
    float* __restrict__ Out)       // [48,48,48,16,16,2]
{
    __shared__ float atoms_lds[1728];   // [k27][n16][q4] q={Ar r0, Ar r1, Ai r0, Ai r1}
    __shared__ float w_lds[4096];       // [f16][n16][cr16], chunk-swizzled by n>>2
    __shared__ float wc_lds[128];       // [f16][c8]
    __shared__ float b_lds[16];
    __shared__ float x_lds[720];        // [dz3][dy3][wx10][c8]
    __shared__ float s_lds[8 * 512];    // per wave: [ri2][n16][cr16], chunk-swizzled by n>>1

    const int tid = threadIdx.x;
    const int bid = blockIdx.x;
    const int d  = bid / (48 * 6);
    const int r0 = bid - d * (48 * 6);
    const int h  = r0 / 6;
    const int ws = r0 - h * 6;
    const int w0 = ws * 8;

    // ---- stage atoms: [k][n][q] ----
    for (int t = tid; t < 1728; t += 512) {
        int k = t >> 6; int rem = t & 63; int n = rem >> 2; int q = rem & 3;
        const float* src = (q >> 1) ? AI : AR;
        atoms_lds[t] = src[k * 32 + (q & 1) * 16 + n];
    }
    // ---- stage w_exp with deg->NH expansion + XOR chunk swizzle ----
    for (int t = tid; t < 4096; t += 512) {
        int f = t >> 8; int n = (t >> 4) & 15; int cr = t & 15;
        int c = cr >> 1; int r = cr & 1;
        int dg = (n >= 9) ? 3 : (n >= 4) ? 2 : (n >= 1) ? 1 : 0;
        float v = Wgt[c * 128 + f * 8 + r * 4 + dg];
        int phys = ((f * 16 + n) << 4) + ((((cr >> 2) ^ ((n >> 2) & 3)) << 2)) + (cr & 3);
        w_lds[phys] = v;
    }
    if (tid < 128) wc_lds[tid] = WC[(tid & 7) * 16 + (tid >> 3)];
    if (tid < 16)  b_lds[tid] = Bc[tid];
    // ---- stage x tile with SAME zero padding ----
    for (int t = tid; t < 720; t += 512) {
        int c = t & 7; int wx = (t >> 3) % 10; int r3 = t / 80;
        int dy = r3 % 3; int dz = r3 / 3;
        int dd = d - 1 + dz, hh = h - 1 + dy, ww = w0 - 1 + wx;
        float v = 0.f;
        if ((unsigned)dd < 48u && (unsigned)hh < 48u && (unsigned)ww < 48u)
            v = X[((dd * 48 + hh) * 48 + ww) * 8 + c];
        x_lds[t] = v;
    }
    __syncthreads();

    const int wave = tid >> 6;
    const int lane = tid & 63;
    const int n = lane & 15;       // harmonic
    const int g = lane >> 4;       // owns c in {2g,2g+1}, r in {0,1} -> cr 4g..4g+3

    // ---- phase 1: depthwise SH conv -> s[cr][n] (4 real + 4 imag per lane) ----
    float sr0 = 0, sr1 = 0, sr2 = 0, sr3 = 0;
    float si0 = 0, si1 = 0, si2 = 0, si3 = 0;
    #pragma unroll
    for (int kz = 0; kz < 3; ++kz)
    #pragma unroll
    for (int ky = 0; ky < 3; ++ky)
    #pragma unroll
    for (int kx = 0; kx < 3; ++kx) {
        const int k = (kz * 3 + ky) * 3 + kx;
        const float2 xv = *(const float2*)&x_lds[(((kz * 3 + ky) * 10) + wave + kx) * 8 + 2 * g];
        const float4 a  = *(const float4*)&atoms_lds[(k * 16 + n) * 4];
        sr0 += xv.x * a.x; sr1 += xv.x * a.y;
        sr2 += xv.y * a.x; sr3 += xv.y * a.y;
        si0 += xv.x * a.z; si1 += xv.x * a.w;
        si2 += xv.y * a.z; si3 += xv.y * a.w;
    }
    // write s rows (chunk g, swizzled)
    {
        float4* s4 = (float4*)s_lds;
        const int phys = g ^ ((n >> 1) & 3);
        s4[wave * 128 +      n * 4 + phys] = make_float4(sr0, sr1, sr2, sr3);
        s4[wave * 128 + 64 + n * 4 + phys] = make_float4(si0, si1, si2, si3);
    }
    __syncthreads();

    // ---- phase 2: mix over (c,r) -> real/imag[f,n] ----
    const float4* s4 = (const float4*)s_lds;
    float4 srr[4], sri[4];
    #pragma unroll
    for (int ch = 0; ch < 4; ++ch) {
        const int phys = ch ^ ((n >> 1) & 3);
        srr[ch] = s4[wave * 128 +      n * 4 + phys];
        sri[ch] = s4[wave * 128 + 64 + n * 4 + phys];
    }

    // central 1x1x1 term (only applied to n==0 lanes)
    float cent[4];
    {
        const int cb = ((1 * 3 + 1) * 10 + wave + 1) * 8;
        const float4 xc0 = *(const float4*)&x_lds[cb];
        const float4 xc1 = *(const float4*)&x_lds[cb + 4];
        #pragma unroll
        for (int fi = 0; fi < 4; ++fi) {
            const int f = 4 * g + fi;
            const float* wcrow = &wc_lds[f * 8];
            float acc = b_lds[f];
            acc += xc0.x * wcrow[0] + xc0.y * wcrow[1] + xc0.z * wcrow[2] + xc0.w * wcrow[3];
            acc += xc1.x * wcrow[4] + xc1.y * wcrow[5] + xc1.z * wcrow[6] + xc1.w * wcrow[7];
            cent[fi] = acc;
        }
    }

    const float4* w4 = (const float4*)w_lds;
    const int out_base = ((d * 48 + h) * 48 + (w0 + wave)) * 512;
    #pragma unroll
    for (int fi = 0; fi < 4; ++fi) {
        const int f = 4 * g + fi;
        float accR = 0.f, accI = 0.f;
        #pragma unroll
        for (int ch = 0; ch < 4; ++ch) {
            const int wp = (f * 16 + n) * 4 + (ch ^ ((n >> 2) & 3));
            const float4 wv = w4[wp];
            const float4 sv = srr[ch];
            const float4 sw = sri[ch];
            accR += wv.x * sv.x + wv.y * sv.y + wv.z * sv.z + wv.w * sv.w;
            accI += wv.x * sw.x + wv.y * sw.y + wv.z * sw.z + wv.w * sw.w;
        }
        if (n == 0) accR += cent[fi];
        *(float2*)&Out[out_base + (f * 16 + n) * 2] = make_float2(accR, accI);
    }
}

extern "C" void kernel_launch(void* const* d_in, const int* in_sizes, int n_in,
                              void* d_out, int out_size, void* d_ws, size_t ws_size,
                              hipStream_t stream) {
    (void)in_sizes; (void)n_in; (void)out_size; (void)d_ws; (void)ws_size;
    const float* x  = (const float*)d_in[0];
    const float* ar = (const float*)d_in[1];
    const float* ai = (const float*)d_in[2];
    const float* w  = (const float*)d_in[3];
    const float* wc = (const float*)d_in[4];
    const float* bc = (const float*)d_in[5];
    float* out = (float*)d_out;
    hipLaunchKernelGGL(bsh_kernel, dim3(NBLK), dim3(512), 0, stream,
                       x, ar, ai, w, wc, bc, out);
}

// Round 2
// 126.153 us; speedup vs baseline: 1.2025x; 1.2025x over previous
//
#include <hip/hip_runtime.h>

// BSHConv3D fused kernel, round 2.
// dims: B=1, D=H=W=48, C=8, K=3, R=2, NH=16, OUT=16.
// out: [48,48,48,16(f),16(n),2(re/im)] fp32, 226 MB.
//
// Kernel 1 (bsh_precompute, 1 block): builds flat constant table in d_ws:
//   [0..4095]    w_exp  [row=f*16+n][physchunk4][e4], physchunk = chunk ^ (n&3)
//   [4096..5823] atoms  [k27][n16][q4], q = {Ar r0, Ar r1, Ai r0, Ai r1}
//   [5824..5951] wc     [f16][c8]
//   [5952..5967] bias   [f16]
// Kernel 2 (bsh_kernel): block = 512 thr = 8 waves, one voxel per wave,
// stages the table with plain float4 copies, phase-1 depthwise SH conv in
// registers, cross-lane shuffle all-gather of s (no LDS round trip),
// phase-2 (c,r)-mix + central term, coalesced float2 stores.

#define NBLK (48*48*6)
#define WS_FLOATS 5968

__global__ __launch_bounds__(512) void bsh_precompute(
    const float* __restrict__ AR,  // [27,2,16]
    const float* __restrict__ AI,  // [27,2,16]
    const float* __restrict__ Wgt, // [8,16,2,4]
    const float* __restrict__ WC,  // [8,16]
    const float* __restrict__ Bc,  // [16]
    float* __restrict__ T)
{
    const int tid = threadIdx.x;
    for (int i = tid; i < 4096; i += 512) {
        int row = i >> 4, f = row >> 4, n = row & 15;
        int pc = (i >> 2) & 3, e = i & 3;
        int chunk = pc ^ (n & 3);
        int cr = chunk * 4 + e, c = cr >> 1, r = cr & 1;
        int dg = (n >= 9) ? 3 : (n >= 4) ? 2 : (n >= 1) ? 1 : 0;
        T[i] = Wgt[c * 128 + f * 8 + r * 4 + dg];
    }
    for (int i = tid; i < 1728; i += 512) {
        int k = i >> 6, n = (i >> 2) & 15, q = i & 3;
        const float* src = (q >> 1) ? AI : AR;
        T[4096 + i] = src[k * 32 + (q & 1) * 16 + n];
    }
    if (tid < 128) T[5824 + tid] = WC[(tid & 7) * 16 + (tid >> 3)];
    if (tid < 16)  T[5952 + tid] = Bc[tid];
}

__device__ inline float4 shfl_xor4(float4 v, int m) {
    return make_float4(__shfl_xor(v.x, m), __shfl_xor(v.y, m),
                       __shfl_xor(v.z, m), __shfl_xor(v.w, m));
}

__global__ __launch_bounds__(512) void bsh_kernel(
    const float* __restrict__ X,   // [48,48,48,8]
    const float* __restrict__ T,   // precomputed table, WS_FLOATS floats
    float* __restrict__ Out)       // [48,48,48,16,16,2]
{
    __shared__ float cst[WS_FLOATS];  // 23.3 KB
    __shared__ float x_lds[720];      // [dz3][dy3][wx10][c8]

    const int tid = threadIdx.x;
    const int bid = blockIdx.x;
    const int d  = bid / (48 * 6);
    const int r0 = bid - d * (48 * 6);
    const int h  = r0 / 6;
    const int w0 = (r0 - h * 6) * 8;

    // ---- stage constant table: straight float4 copies ----
    {
        const float4* t4 = (const float4*)T;
        float4* c4 = (float4*)cst;
        #pragma unroll
        for (int i = 0; i < 3; ++i) {
            int idx = tid + i * 512;
            if (idx < WS_FLOATS / 4) c4[idx] = t4[idx];
        }
        // ---- stage x tile (SAME zero padding), 180 float4 ----
        if (tid < 180) {
            int r3 = tid / 20, rem = tid - r3 * 20;
            int wx = rem >> 1, c0 = (rem & 1) * 4;
            int dz = r3 / 3, dy = r3 - dz * 3;
            int dd = d - 1 + dz, hh = h - 1 + dy, ww = w0 - 1 + wx;
            float4 v = make_float4(0.f, 0.f, 0.f, 0.f);
            if ((unsigned)dd < 48u && (unsigned)hh < 48u && (unsigned)ww < 48u)
                v = *(const float4*)&X[(((dd * 48 + hh) * 48 + ww) * 8) + c0];
            *(float4*)&x_lds[tid * 4] = v;
        }
    }
    __syncthreads();

    const int wave = tid >> 6;
    const int lane = tid & 63;
    const int n = lane & 15;       // harmonic
    const int g = lane >> 4;       // owns cr chunk g = {c=2g,2g+1} x {r=0,1}

    const float* atoms_lds = cst + 4096;
    const float* wc_lds    = cst + 5824;
    const float* b_lds     = cst + 5952;

    // ---- phase 1: depthwise SH conv -> s chunk g (4 real + 4 imag) ----
    float sr0 = 0, sr1 = 0, sr2 = 0, sr3 = 0;
    float si0 = 0, si1 = 0, si2 = 0, si3 = 0;
    #pragma unroll
    for (int kz = 0; kz < 3; ++kz)
    #pragma unroll
    for (int ky = 0; ky < 3; ++ky)
    #pragma unroll
    for (int kx = 0; kx < 3; ++kx) {
        const int k = (kz * 3 + ky) * 3 + kx;
        const float2 xv = *(const float2*)&x_lds[(((kz * 3 + ky) * 10) + wave + kx) * 8 + 2 * g];
        const float4 a  = *(const float4*)&atoms_lds[k * 64 + n * 4];
        sr0 += xv.x * a.x; sr1 += xv.x * a.y;
        sr2 += xv.y * a.x; sr3 += xv.y * a.y;
        si0 += xv.x * a.z; si1 += xv.x * a.w;
        si2 += xv.y * a.z; si3 += xv.y * a.w;
    }

    // ---- cross-lane all-gather of s across the 4 g-lanes sharing n ----
    // rel chunk r holds absolute chunk (g ^ r)
    const float4 sR0 = make_float4(sr0, sr1, sr2, sr3);
    const float4 sI0 = make_float4(si0, si1, si2, si3);
    const float4 sR1 = shfl_xor4(sR0, 16), sI1 = shfl_xor4(sI0, 16);
    const float4 sR2 = shfl_xor4(sR0, 32), sI2 = shfl_xor4(sI0, 32);
    const float4 sR3 = shfl_xor4(sR1, 32), sI3 = shfl_xor4(sI1, 32);

    // ---- central 1x1x1 term (added to n==0 real) ----
    float cent[4];
    {
        const int cb = ((1 * 3 + 1) * 10 + wave + 1) * 8;
        const float4 xc0 = *(const float4*)&x_lds[cb];
        const float4 xc1 = *(const float4*)&x_lds[cb + 4];
        #pragma unroll
        for (int fi = 0; fi < 4; ++fi) {
            const int f = 4 * g + fi;
            const float* wcrow = &wc_lds[f * 8];
            float acc = b_lds[f];
            acc += xc0.x * wcrow[0] + xc0.y * wcrow[1] + xc0.z * wcrow[2] + xc0.w * wcrow[3];
            acc += xc1.x * wcrow[4] + xc1.y * wcrow[5] + xc1.z * wcrow[6] + xc1.w * wcrow[7];
            cent[fi] = acc;
        }
    }

    // ---- phase 2: mix over (c,r) ----
    const float4* w4 = (const float4*)cst;
    const int gx = g ^ (n & 3);
    const int out_base = ((d * 48 + h) * 48 + (w0 + wave)) * 512;
    #pragma unroll
    for (int fi = 0; fi < 4; ++fi) {
        const int f = 4 * g + fi;
        const int rb = (f * 16 + n) * 4;
        const float4 w0v = w4[rb + (gx ^ 0)];   // abs chunk g
        const float4 w1v = w4[rb + (gx ^ 1)];   // abs chunk g^1
        const float4 w2v = w4[rb + (gx ^ 2)];   // abs chunk g^2
        const float4 w3v = w4[rb + (gx ^ 3)];   // abs chunk g^3
        float accR = w0v.x * sR0.x + w0v.y * sR0.y + w0v.z * sR0.z + w0v.w * sR0.w
                   + w1v.x * sR1.x + w1v.y * sR1.y + w1v.z * sR1.z + w1v.w * sR1.w
                   + w2v.x * sR2.x + w2v.y * sR2.y + w2v.z * sR2.z + w2v.w * sR2.w
                   + w3v.x * sR3.x + w3v.y * sR3.y + w3v.z * sR3.z + w3v.w * sR3.w;
        float accI = w0v.x * sI0.x + w0v.y * sI0.y + w0v.z * sI0.z + w0v.w * sI0.w
                   + w1v.x * sI1.x + w1v.y * sI1.y + w1v.z * sI1.z + w1v.w * sI1.w
                   + w2v.x * sI2.x + w2v.y * sI2.y + w2v.z * sI2.z + w2v.w * sI2.w
                   + w3v.x * sI3.x + w3v.y * sI3.y + w3v.z * sI3.z + w3v.w * sI3.w;
        if (n == 0) accR += cent[fi];
        *(float2*)&Out[out_base + (f * 16 + n) * 2] = make_float2(accR, accI);
    }
}

extern "C" void kernel_launch(void* const* d_in, const int* in_sizes, int n_in,
                              void* d_out, int out_size, void* d_ws, size_t ws_size,
                              hipStream_t stream) {
    (void)in_sizes; (void)n_in; (void)out_size; (void)ws_size;
    const float* x  = (const float*)d_in[0];
    const float* ar = (const float*)d_in[1];
    const float* ai = (const float*)d_in[2];
    const float* w  = (const float*)d_in[3];
    const float* wc = (const float*)d_in[4];
    const float* bc = (const float*)d_in[5];
    float* out = (float*)d_out;
    float* tbl = (float*)d_ws;

    hipLaunchKernelGGL(bsh_precompute, dim3(1), dim3(512), 0, stream,
                       ar, ai, w, wc, bc, tbl);
    hipLaunchKernelGGL(bsh_kernel, dim3(NBLK), dim3(512), 0, stream,
                       x, tbl, out);
}

// Round 3
// 100.207 us; speedup vs baseline: 1.5138x; 1.2589x over previous
//
#include <hip/hip_runtime.h>

// BSHConv3D fused kernel, round 3: phase-1 depthwise SH conv via MFMA (fp16),
// phase-2 (c,r)-mix on VALU fp32 with 2-voxel w-amortization.
// dims: B=1, D=H=W=48, C=8, K=3, R=2, NH=16, OUT=16. out 226 MB fp32.
//
// Block = 512 thr = 8 waves, 16 voxels (w-strip). Grid = 48*48*3.
// d_ws float layout:
//   [0..4095]     w_exp: [row=f*16+n][slot4][e4], slot s holds cr-chunk s^(n&3)
//   [4096..5119]  B1 frag table (u32 fp16-pairs): [(t*2+ch)*64+lane]*2+dw
//                 t: r=t&1, reim=t>>1; k = ch*16 + (lane>>4)*4 + j; col n = lane&15
//   [5120..5247]  wc [f16][c8]
//   [5248..5263]  bias[16]

typedef _Float16 half4_t __attribute__((ext_vector_type(4)));
typedef float floatx4 __attribute__((ext_vector_type(4)));

#define NBLK (48*48*3)
#define T_B1   4096
#define T_WC   5120
#define T_BIAS 5248

__global__ __launch_bounds__(512) void bsh_precompute(
    const float* __restrict__ AR,  // [27,2,16]
    const float* __restrict__ AI,  // [27,2,16]
    const float* __restrict__ Wgt, // [8,16,2,4]
    const float* __restrict__ WC,  // [8,16]
    const float* __restrict__ Bc,  // [16]
    float* __restrict__ T)
{
    const int tid = threadIdx.x;
    // w_exp table (same layout as round 2)
    for (int i = tid; i < 4096; i += 512) {
        int row = i >> 4, f = row >> 4, n = row & 15;
        int pc = (i >> 2) & 3, e = i & 3;
        int chunk = pc ^ (n & 3);
        int cr = chunk * 4 + e, c = cr >> 1, r = cr & 1;
        int dg = (n >= 9) ? 3 : (n >= 4) ? 2 : (n >= 1) ? 1 : 0;
        T[i] = Wgt[c * 128 + f * 8 + r * 4 + dg];
    }
    // B1 MFMA fragment table (atoms as fp16, fragment-ordered)
    for (int i = tid; i < 1024; i += 512) {
        int dw = i & 1, lane = (i >> 1) & 63, tc = i >> 7;
        int t = tc >> 1, ch = tc & 1;
        int n = lane & 15, r = t & 1;
        const float* src = (t >> 1) ? AI : AR;
        unsigned out = 0;
        #pragma unroll
        for (int jj = 0; jj < 2; ++jj) {
            int j = dw * 2 + jj;
            int k = ch * 16 + (lane >> 4) * 4 + j;
            float v = (k < 27) ? src[k * 32 + r * 16 + n] : 0.f;
            _Float16 hh = (_Float16)v;
            unsigned short bits = __builtin_bit_cast(unsigned short, hh);
            out |= ((unsigned)bits) << (16 * jj);
        }
        ((unsigned*)T)[T_B1 + i] = out;
    }
    if (tid < 128) T[T_WC + tid] = WC[(tid & 7) * 16 + (tid >> 3)];
    if (tid < 16)  T[T_BIAS + tid] = Bc[tid];
}

__device__ inline float dot4(float4 a, float4 b) {
    return a.x * b.x + a.y * b.y + a.z * b.z + a.w * b.w;
}

__global__ __launch_bounds__(512) void bsh_kernel(
    const float* __restrict__ X,   // [48,48,48,8]
    const float* __restrict__ T,
    float* __restrict__ Out)       // [48,48,48,16,16,2]
{
    __shared__ __align__(16) float cst[4240];            // w_exp + wc + bias
    __shared__ __align__(16) float x_lds[1296];          // [dz3][dy3][wx18][c8]
    __shared__ __align__(16) _Float16 im2[8 * 17 * 32];  // [c][17v][32k], quad^(c&3)
    __shared__ __align__(16) float feat[16 * 512];       // [v][reim2][n16][cr16], slot^(n&3)

    const int tid = threadIdx.x;
    const int lane = tid & 63;
    const int wave = tid >> 6;
    const int bid = blockIdx.x;
    const int d  = bid / (48 * 3);
    const int r0 = bid - d * (48 * 3);
    const int h  = r0 / 3;
    const int w0 = (r0 - h * 3) * 16;

    // ---- B1 fragments: global -> regs (L2-resident table) ----
    uint2 b1u[8];
    {
        const uint2* tb = (const uint2*)((const unsigned*)T + T_B1);
        #pragma unroll
        for (int tc = 0; tc < 8; ++tc) b1u[tc] = tb[tc * 64 + lane];
    }

    // ---- stage constant table ----
    {
        const float4* t4 = (const float4*)T;
        float4* c4 = (float4*)cst;
        #pragma unroll
        for (int it = 0; it < 3; ++it) {
            int i = tid + it * 512;
            if (i < 1060) c4[i] = (i < 1024) ? t4[i] : t4[i + 256];
        }
    }
    // ---- stage x tile (SAME zero padding): 324 float4 ----
    if (tid < 324) {
        int c4i = tid & 1, wx = (tid >> 1) % 18, row = tid / 36;
        int dz = row / 3, dy = row % 3;
        int dd = d - 1 + dz, hh = h - 1 + dy, ww = w0 - 1 + wx;
        float4 v = make_float4(0.f, 0.f, 0.f, 0.f);
        if ((unsigned)dd < 48u && (unsigned)hh < 48u && (unsigned)ww < 48u)
            v = *(const float4*)&X[(((dd * 48 + hh) * 48 + ww) * 8) + c4i * 4];
        *(float4*)&x_lds[((dz * 3 + dy) * 18 + wx) * 8 + c4i * 4] = v;
    }
    __syncthreads();

    // ---- im2col build: fp16 [c][17v][32k], quad-swizzled ----
    {
        int v = tid >> 5, c = (tid >> 2) & 7, ko = tid & 3;
        unsigned qw[4];
        #pragma unroll
        for (int jp = 0; jp < 4; ++jp) {
            unsigned bits2 = 0;
            #pragma unroll
            for (int jj = 0; jj < 2; ++jj) {
                int j = jp * 2 + jj;
                int k = 8 * ko + j;
                float val = 0.f;
                if (k < 27) {
                    int kz = k / 9, r9 = k - 9 * kz;
                    int ky = r9 / 3, kx = r9 - 3 * ky;
                    val = x_lds[((kz * 3 + ky) * 18 + (v + kx)) * 8 + c];
                }
                _Float16 hh = (_Float16)val;
                bits2 |= ((unsigned)__builtin_bit_cast(unsigned short, hh)) << (16 * jj);
            }
            qw[jp] = bits2;
        }
        char* rowp = (char*)&im2[(c * 17 + v) * 32];
        *(uint2*)(rowp + ((((2 * ko + 0) ^ (c & 3)) << 3))) = make_uint2(qw[0], qw[1]);
        *(uint2*)(rowp + ((((2 * ko + 1) ^ (c & 3)) << 3))) = make_uint2(qw[2], qw[3]);
    }
    __syncthreads();

    // ---- phase 1: MFMA depthwise SH conv, wave = Mtile (2 voxels x 8c) ----
    {
        const int m = lane & 15, kg = lane >> 4;
        const int pc = m & 7, pv = 2 * wave + (m >> 3);
        const char* rp = (const char*)&im2[(pc * 17 + pv) * 32];
        half4_t A0 = *(const half4_t*)(rp + (((0 + kg) ^ (pc & 3)) << 3));
        half4_t A1 = *(const half4_t*)(rp + (((4 + kg) ^ (pc & 3)) << 3));

        floatx4 D0 = {0.f,0.f,0.f,0.f}, D1 = {0.f,0.f,0.f,0.f};
        floatx4 D2 = {0.f,0.f,0.f,0.f}, D3 = {0.f,0.f,0.f,0.f};
        half4_t B00 = __builtin_bit_cast(half4_t, b1u[0]);
        half4_t B01 = __builtin_bit_cast(half4_t, b1u[1]);
        half4_t B10 = __builtin_bit_cast(half4_t, b1u[2]);
        half4_t B11 = __builtin_bit_cast(half4_t, b1u[3]);
        half4_t B20 = __builtin_bit_cast(half4_t, b1u[4]);
        half4_t B21 = __builtin_bit_cast(half4_t, b1u[5]);
        half4_t B30 = __builtin_bit_cast(half4_t, b1u[6]);
        half4_t B31 = __builtin_bit_cast(half4_t, b1u[7]);
        D0 = __builtin_amdgcn_mfma_f32_16x16x16f16(A0, B00, D0, 0, 0, 0);
        D0 = __builtin_amdgcn_mfma_f32_16x16x16f16(A1, B01, D0, 0, 0, 0);
        D1 = __builtin_amdgcn_mfma_f32_16x16x16f16(A0, B10, D1, 0, 0, 0);
        D1 = __builtin_amdgcn_mfma_f32_16x16x16f16(A1, B11, D1, 0, 0, 0);
        D2 = __builtin_amdgcn_mfma_f32_16x16x16f16(A0, B20, D2, 0, 0, 0);
        D2 = __builtin_amdgcn_mfma_f32_16x16x16f16(A1, B21, D2, 0, 0, 0);
        D3 = __builtin_amdgcn_mfma_f32_16x16x16f16(A0, B30, D3, 0, 0, 0);
        D3 = __builtin_amdgcn_mfma_f32_16x16x16f16(A1, B31, D3, 0, 0, 0);

        // feat write: [v][reim][n][cr16] with cr-chunk slot = (c>>1)^(n&3)
        const int n = lane & 15;
        #pragma unroll
        for (int reg = 0; reg < 4; ++reg) {
            int mD = kg * 4 + reg;
            int vD = 2 * wave + (mD >> 3), cD = mD & 7;
            int base = vD * 512 + n * 16 + (((cD >> 1) ^ (n & 3)) << 2) + ((cD & 1) << 1);
            *(float2*)&feat[base]       = make_float2(D0[reg], D1[reg]);  // re: r0,r1
            *(float2*)&feat[base + 256] = make_float2(D2[reg], D3[reg]);  // im: r0,r1
        }
    }
    __syncthreads();

    // ---- phase 2: mix over (c,r), wave handles voxels va, vb ----
    {
        const int n = lane & 15, g = lane >> 4;
        const int va = 2 * wave, vb = va + 1;
        const int msk = n & 3;
        const int sl0 = g ^ msk, sl1 = sl0 ^ 1, sl2 = sl0 ^ 2, sl3 = sl0 ^ 3;
        const float4* f4 = (const float4*)feat;
        const int ba = va * 128 + n * 4, bb = vb * 128 + n * 4;
        // slot sl_rr holds abs cr-chunk g^rr (both feat and w tables)
        float4 sra0 = f4[ba + sl0], sra1 = f4[ba + sl1], sra2 = f4[ba + sl2], sra3 = f4[ba + sl3];
        float4 sia0 = f4[ba + 64 + sl0], sia1 = f4[ba + 64 + sl1], sia2 = f4[ba + 64 + sl2], sia3 = f4[ba + 64 + sl3];
        float4 srb0 = f4[bb + sl0], srb1 = f4[bb + sl1], srb2 = f4[bb + sl2], srb3 = f4[bb + sl3];
        float4 sib0 = f4[bb + 64 + sl0], sib1 = f4[bb + 64 + sl1], sib2 = f4[bb + 64 + sl2], sib3 = f4[bb + 64 + sl3];

        float centa[4] = {0.f,0.f,0.f,0.f}, centb[4] = {0.f,0.f,0.f,0.f};
        if (n == 0) {
            const float* wc_lds = cst + 4096;
            const float* b_lds  = cst + 4224;
            const int cba = (72 + va + 1) * 8, cbb = (72 + vb + 1) * 8;
            float4 xa0 = *(const float4*)&x_lds[cba], xa1 = *(const float4*)&x_lds[cba + 4];
            float4 xb0 = *(const float4*)&x_lds[cbb], xb1 = *(const float4*)&x_lds[cbb + 4];
            #pragma unroll
            for (int fi = 0; fi < 4; ++fi) {
                int f = 4 * g + fi;
                float4 wq0 = *(const float4*)&wc_lds[f * 8];
                float4 wq1 = *(const float4*)&wc_lds[f * 8 + 4];
                centa[fi] = b_lds[f] + dot4(xa0, wq0) + dot4(xa1, wq1);
                centb[fi] = b_lds[f] + dot4(xb0, wq0) + dot4(xb1, wq1);
            }
        }

        const float4* w4c = (const float4*)cst;
        const int obase_a = ((d * 48 + h) * 48 + (w0 + va)) * 512;
        const int obase_b = obase_a + 512;
        #pragma unroll
        for (int fi = 0; fi < 4; ++fi) {
            int f = 4 * g + fi;
            int rb = (f * 16 + n) * 4;
            float4 wv0 = w4c[rb + sl0], wv1 = w4c[rb + sl1];
            float4 wv2 = w4c[rb + sl2], wv3 = w4c[rb + sl3];
            float aRa = dot4(wv0, sra0) + dot4(wv1, sra1) + dot4(wv2, sra2) + dot4(wv3, sra3);
            float aIa = dot4(wv0, sia0) + dot4(wv1, sia1) + dot4(wv2, sia2) + dot4(wv3, sia3);
            float aRb = dot4(wv0, srb0) + dot4(wv1, srb1) + dot4(wv2, srb2) + dot4(wv3, srb3);
            float aIb = dot4(wv0, sib0) + dot4(wv1, sib1) + dot4(wv2, sib2) + dot4(wv3, sib3);
            aRa += centa[fi];
            aRb += centb[fi];
            *(float2*)&Out[obase_a + (f * 16 + n) * 2] = make_float2(aRa, aIa);
            *(float2*)&Out[obase_b + (f * 16 + n) * 2] = make_float2(aRb, aIb);
        }
    }
}

extern "C" void kernel_launch(void* const* d_in, const int* in_sizes, int n_in,
                              void* d_out, int out_size, void* d_ws, size_t ws_size,
                              hipStream_t stream) {
    (void)in_sizes; (void)n_in; (void)out_size; (void)ws_size;
    const float* x  = (const float*)d_in[0];
    const float* ar = (const float*)d_in[1];
    const float* ai = (const float*)d_in[2];
    const float* w  = (const float*)d_in[3];
    const float* wc = (const float*)d_in[4];
    const float* bc = (const float*)d_in[5];
    float* out = (float*)d_out;
    float* tbl = (float*)d_ws;

    hipLaunchKernelGGL(bsh_precompute, dim3(1), dim3(512), 0, stream,
                       ar, ai, w, wc, bc, tbl);
    hipLaunchKernelGGL(bsh_kernel, dim3(NBLK), dim3(512), 0, stream,
                       x, tbl, out);
}

// Round 4
// 61.898 us; speedup vs baseline: 2.4507x; 1.6189x over previous
//
#include <hip/hip_runtime.h>

// BSHConv3D as ONE im2col GEMM, round 4.
// out[v=110592][col=512] = A[v][kap=224] * Mb[kap][512]  (fp16 in, fp32 accum)
//   kap = k*8+c (k=0..27, k27 = bias row: A=1 at c==7), col = f*32+n*2+ri
//   Mb[(k,c)][(f,n,ri)] = sum_r atoms_{ri}[k,r,n]*w[c,f,r,dg(n)]
//                         + (k==13,n==0,ri==0)? wc[c,f]  ; k==27 row: bias[f] at (f,0,re),c==7
// Mb precomputed FRAGMENT-ORDERED in d_ws (fp16, 224 KB), loaded per-wave from L2.
// Main kernel: block=512thr=8 waves, tile M96 x N256; wave M48 x N64 (3x4 16x16 tiles).
// im2col A-tile in LDS [96][232] fp16 (row pad 232 breaks bank collisions).

typedef _Float16 half4_t __attribute__((ext_vector_type(4)));
typedef float floatx4 __attribute__((ext_vector_type(4)));

#define B_U64_SLOTS (14 * 32 * 64)             // 28672 (t14, ntile32, lane64)
#define WS_BYTES_NEEDED (B_U64_SLOTS * 8)      // 229376

__device__ inline unsigned short f2h(float v) {
    return __builtin_bit_cast(unsigned short, (_Float16)v);
}
__device__ inline unsigned pk2(float a, float b) {
    return (unsigned)f2h(a) | ((unsigned)f2h(b) << 16);
}

// ---------------- GEMM-path precompute ----------------
__global__ __launch_bounds__(512) void bsh_precompute_gemm(
    const float* __restrict__ AR,  // [27,2,16]
    const float* __restrict__ AI,  // [27,2,16]
    const float* __restrict__ Wgt, // [8,16,2,4]
    const float* __restrict__ WC,  // [8,16]
    const float* __restrict__ Bc,  // [16]
    unsigned long long* __restrict__ TB)
{
    int s = blockIdx.x * 512 + threadIdx.x;
    if (s >= B_U64_SLOTS) return;
    int l = s & 63, ntg = (s >> 6) & 31, t = s >> 11;
    int col = 16 * ntg + (l & 15);
    int f = col >> 5, n = (col >> 1) & 15, ri = col & 1;
    int dg = (n >= 9) ? 3 : (n >= 4) ? 2 : (n >= 1) ? 1 : 0;
    const float* atom = ri ? AI : AR;
    unsigned long long pack = 0;
    #pragma unroll
    for (int j = 0; j < 4; ++j) {
        int kap = 16 * t + 4 * (l >> 4) + j;
        int k = kap >> 3, c = kap & 7;
        float v = 0.f;
        if (k < 27) {
            float w0 = Wgt[((c * 16 + f) * 2 + 0) * 4 + dg];
            float w1 = Wgt[((c * 16 + f) * 2 + 1) * 4 + dg];
            v = atom[k * 32 + n] * w0 + atom[k * 32 + 16 + n] * w1;
            if (k == 13 && n == 0 && ri == 0) v += WC[c * 16 + f];
        } else {                      // bias row
            if (c == 7 && n == 0 && ri == 0) v = Bc[f];
        }
        pack |= ((unsigned long long)f2h(v)) << (16 * j);
    }
    TB[s] = pack;
}

// ---------------- main GEMM kernel ----------------
__global__ __launch_bounds__(512) void bsh_gemm(
    const float* __restrict__ X,   // [48,48,48,8]
    const unsigned long long* __restrict__ TB,
    float* __restrict__ Out)       // [110592,512]
{
    __shared__ _Float16 A_lds[96 * 232];   // 43.5 KB, row stride 232 fp16 = 464 B

    const int tid = threadIdx.x;
    const int bid = blockIdx.x;
    const int nb = bid & 1;        // N half (256 cols)
    const int rb = bid >> 1;       // 0..1151, covers voxels rb*96..rb*96+95
    const int d  = rb / 24;
    const int hp = rb - 24 * d;    // h pair: rows 2hp, 2hp+1

    // ---- im2col build: cells [k28][v96], 8 channels each -> 2 x b64 writes ----
    #pragma unroll
    for (int i = 0; i < 6; ++i) {
        int cell = tid + i * 512;
        if (cell < 2688) {
            int k = cell / 96;
            int v = cell - 96 * k;
            unsigned x01 = 0, x23 = 0, x45 = 0, x67 = 0;
            if (k == 27) {
                x67 = 0x3C000000u;             // A[v][223] = 1.0h (bias column)
            } else {
                int kz = k / 9, r9 = k - 9 * kz;
                int ky = r9 / 3, kx = r9 - 3 * ky;
                int hl = (v >= 48) ? 1 : 0;
                int dd = d - 1 + kz;
                int hh = 2 * hp + hl - 1 + ky;
                int ww = v - 48 * hl - 1 + kx;
                if ((unsigned)dd < 48u && (unsigned)hh < 48u && (unsigned)ww < 48u) {
                    const float* px = &X[(((dd * 48 + hh) * 48) + ww) * 8];
                    float4 a = *(const float4*)px;
                    float4 b = *(const float4*)(px + 4);
                    x01 = pk2(a.x, a.y); x23 = pk2(a.z, a.w);
                    x45 = pk2(b.x, b.y); x67 = pk2(b.z, b.w);
                }
            }
            char* wp = (char*)A_lds + v * 464 + k * 16;
            *(uint2*)wp       = make_uint2(x01, x23);
            *(uint2*)(wp + 8) = make_uint2(x45, x67);
        }
    }
    __syncthreads();

    const int lane = tid & 63, wave = tid >> 6;
    const int ms = wave >> 2, ns = wave & 3;       // wave tile: rows 48ms.., cols 64ns..
    const int kg = lane >> 4, lr = lane & 15;

    floatx4 D[3][4];
    #pragma unroll
    for (int mt = 0; mt < 3; ++mt)
        #pragma unroll
        for (int nt = 0; nt < 4; ++nt)
            D[mt][nt] = (floatx4){0.f, 0.f, 0.f, 0.f};

    // B-frag base: slot index (t*32 + ntg)*64 + lane, ntg = nb*16 + ns*4 + nt
    const unsigned long long* bp = TB + ((size_t)(nb * 16 + ns * 4) * 64 + lane);
    const char* arow = (const char*)A_lds + (48 * ms + lr) * 464 + kg * 8;

    unsigned long long Bbuf[2][4];
    #pragma unroll
    for (int nt = 0; nt < 4; ++nt) Bbuf[0][nt] = bp[(size_t)nt * 64];

    #pragma unroll
    for (int t = 0; t < 14; ++t) {
        if (t < 13) {
            #pragma unroll
            for (int nt = 0; nt < 4; ++nt)
                Bbuf[(t + 1) & 1][nt] = bp[(size_t)((t + 1) * 32 + nt) * 64];
        }
        half4_t a0 = *(const half4_t*)(arow + 32 * t);
        half4_t a1 = *(const half4_t*)(arow + 16 * 464 + 32 * t);
        half4_t a2 = *(const half4_t*)(arow + 32 * 464 + 32 * t);
        #pragma unroll
        for (int nt = 0; nt < 4; ++nt) {
            half4_t bf = __builtin_bit_cast(half4_t, Bbuf[t & 1][nt]);
            D[0][nt] = __builtin_amdgcn_mfma_f32_16x16x16f16(a0, bf, D[0][nt], 0, 0, 0);
            D[1][nt] = __builtin_amdgcn_mfma_f32_16x16x16f16(a1, bf, D[1][nt], 0, 0, 0);
            D[2][nt] = __builtin_amdgcn_mfma_f32_16x16x16f16(a2, bf, D[2][nt], 0, 0, 0);
        }
    }

    // ---- stores: D row m = 4*kg+reg, col = lr (verified mapping) ----
    float* ob = Out + (size_t)(rb * 96 + 48 * ms + 4 * kg) * 512
                    + nb * 256 + ns * 64 + lr;
    #pragma unroll
    for (int mt = 0; mt < 3; ++mt)
        #pragma unroll
        for (int reg = 0; reg < 4; ++reg) {
            float* orow = ob + (size_t)(16 * mt + reg) * 512;
            orow[0]  = D[mt][0][reg];
            orow[16] = D[mt][1][reg];
            orow[32] = D[mt][2][reg];
            orow[48] = D[mt][3][reg];
        }
}

// ================= fallback path (round-2 kernel, needs only 24 KB ws) =================
#define FB_NBLK (48*48*6)
#define FB_WS_FLOATS 5968

__global__ __launch_bounds__(512) void fb_precompute(
    const float* __restrict__ AR, const float* __restrict__ AI,
    const float* __restrict__ Wgt, const float* __restrict__ WC,
    const float* __restrict__ Bc, float* __restrict__ T)
{
    const int tid = threadIdx.x;
    for (int i = tid; i < 4096; i += 512) {
        int row = i >> 4, f = row >> 4, n = row & 15;
        int pc = (i >> 2) & 3, e = i & 3;
        int chunk = pc ^ (n & 3);
        int cr = chunk * 4 + e, c = cr >> 1, r = cr & 1;
        int dg = (n >= 9) ? 3 : (n >= 4) ? 2 : (n >= 1) ? 1 : 0;
        T[i] = Wgt[c * 128 + f * 8 + r * 4 + dg];
    }
    for (int i = tid; i < 1728; i += 512) {
        int k = i >> 6, n = (i >> 2) & 15, q = i & 3;
        const float* src = (q >> 1) ? AI : AR;
        T[4096 + i] = src[k * 32 + (q & 1) * 16 + n];
    }
    if (tid < 128) T[5824 + tid] = WC[(tid & 7) * 16 + (tid >> 3)];
    if (tid < 16)  T[5952 + tid] = Bc[tid];
}

__device__ inline float4 fb_shfl_xor4(float4 v, int m) {
    return make_float4(__shfl_xor(v.x, m), __shfl_xor(v.y, m),
                       __shfl_xor(v.z, m), __shfl_xor(v.w, m));
}

__global__ __launch_bounds__(512) void fb_kernel(
    const float* __restrict__ X, const float* __restrict__ T,
    float* __restrict__ Out)
{
    __shared__ float cst[FB_WS_FLOATS];
    __shared__ float x_lds[720];

    const int tid = threadIdx.x;
    const int bid = blockIdx.x;
    const int d  = bid / (48 * 6);
    const int r0 = bid - d * (48 * 6);
    const int h  = r0 / 6;
    const int w0 = (r0 - h * 6) * 8;

    {
        const float4* t4 = (const float4*)T;
        float4* c4 = (float4*)cst;
        #pragma unroll
        for (int i = 0; i < 3; ++i) {
            int idx = tid + i * 512;
            if (idx < FB_WS_FLOATS / 4) c4[idx] = t4[idx];
        }
        if (tid < 180) {
            int r3 = tid / 20, rem = tid - r3 * 20;
            int wx = rem >> 1, c0 = (rem & 1) * 4;
            int dz = r3 / 3, dy = r3 - dz * 3;
            int dd = d - 1 + dz, hh = h - 1 + dy, ww = w0 - 1 + wx;
            float4 v = make_float4(0.f, 0.f, 0.f, 0.f);
            if ((unsigned)dd < 48u && (unsigned)hh < 48u && (unsigned)ww < 48u)
                v = *(const float4*)&X[(((dd * 48 + hh) * 48 + ww) * 8) + c0];
            *(float4*)&x_lds[tid * 4] = v;
        }
    }
    __syncthreads();

    const int wave = tid >> 6, lane = tid & 63;
    const int n = lane & 15, g = lane >> 4;
    const float* atoms_lds = cst + 4096;
    const float* wc_lds    = cst + 5824;
    const float* b_lds     = cst + 5952;

    float sr0 = 0, sr1 = 0, sr2 = 0, sr3 = 0;
    float si0 = 0, si1 = 0, si2 = 0, si3 = 0;
    #pragma unroll
    for (int kz = 0; kz < 3; ++kz)
    #pragma unroll
    for (int ky = 0; ky < 3; ++ky)
    #pragma unroll
    for (int kx = 0; kx < 3; ++kx) {
        const int k = (kz * 3 + ky) * 3 + kx;
        const float2 xv = *(const float2*)&x_lds[(((kz * 3 + ky) * 10) + wave + kx) * 8 + 2 * g];
        const float4 a  = *(const float4*)&atoms_lds[k * 64 + n * 4];
        sr0 += xv.x * a.x; sr1 += xv.x * a.y;
        sr2 += xv.y * a.x; sr3 += xv.y * a.y;
        si0 += xv.x * a.z; si1 += xv.x * a.w;
        si2 += xv.y * a.z; si3 += xv.y * a.w;
    }
    const float4 sR0 = make_float4(sr0, sr1, sr2, sr3);
    const float4 sI0 = make_float4(si0, si1, si2, si3);
    const float4 sR1 = fb_shfl_xor4(sR0, 16), sI1 = fb_shfl_xor4(sI0, 16);
    const float4 sR2 = fb_shfl_xor4(sR0, 32), sI2 = fb_shfl_xor4(sI0, 32);
    const float4 sR3 = fb_shfl_xor4(sR1, 32), sI3 = fb_shfl_xor4(sI1, 32);

    float cent[4];
    {
        const int cb = ((1 * 3 + 1) * 10 + wave + 1) * 8;
        const float4 xc0 = *(const float4*)&x_lds[cb];
        const float4 xc1 = *(const float4*)&x_lds[cb + 4];
        #pragma unroll
        for (int fi = 0; fi < 4; ++fi) {
            const int f = 4 * g + fi;
            const float* wcr = &wc_lds[f * 8];
            cent[fi] = b_lds[f]
                + xc0.x * wcr[0] + xc0.y * wcr[1] + xc0.z * wcr[2] + xc0.w * wcr[3]
                + xc1.x * wcr[4] + xc1.y * wcr[5] + xc1.z * wcr[6] + xc1.w * wcr[7];
        }
    }

    const float4* w4 = (const float4*)cst;
    const int gx = g ^ (n & 3);
    const int out_base = ((d * 48 + h) * 48 + (w0 + wave)) * 512;
    #pragma unroll
    for (int fi = 0; fi < 4; ++fi) {
        const int f = 4 * g + fi;
        const int rb2 = (f * 16 + n) * 4;
        const float4 w0v = w4[rb2 + (gx ^ 0)];
        const float4 w1v = w4[rb2 + (gx ^ 1)];
        const float4 w2v = w4[rb2 + (gx ^ 2)];
        const float4 w3v = w4[rb2 + (gx ^ 3)];
        float accR = w0v.x*sR0.x + w0v.y*sR0.y + w0v.z*sR0.z + w0v.w*sR0.w
                   + w1v.x*sR1.x + w1v.y*sR1.y + w1v.z*sR1.z + w1v.w*sR1.w
                   + w2v.x*sR2.x + w2v.y*sR2.y + w2v.z*sR2.z + w2v.w*sR2.w
                   + w3v.x*sR3.x + w3v.y*sR3.y + w3v.z*sR3.z + w3v.w*sR3.w;
        float accI = w0v.x*sI0.x + w0v.y*sI0.y + w0v.z*sI0.z + w0v.w*sI0.w
                   + w1v.x*sI1.x + w1v.y*sI1.y + w1v.z*sI1.z + w1v.w*sI1.w
                   + w2v.x*sI2.x + w2v.y*sI2.y + w2v.z*sI2.z + w2v.w*sI2.w
                   + w3v.x*sI3.x + w3v.y*sI3.y + w3v.z*sI3.z + w3v.w*sI3.w;
        if (n == 0) accR += cent[fi];
        *(float2*)&Out[out_base + (f * 16 + n) * 2] = make_float2(accR, accI);
    }
}

extern "C" void kernel_launch(void* const* d_in, const int* in_sizes, int n_in,
                              void* d_out, int out_size, void* d_ws, size_t ws_size,
                              hipStream_t stream) {
    (void)in_sizes; (void)n_in; (void)out_size;
    const float* x  = (const float*)d_in[0];
    const float* ar = (const float*)d_in[1];
    const float* ai = (const float*)d_in[2];
    const float* w  = (const float*)d_in[3];
    const float* wc = (const float*)d_in[4];
    const float* bc = (const float*)d_in[5];
    float* out = (float*)d_out;

    if (ws_size >= (size_t)WS_BYTES_NEEDED) {
        unsigned long long* tb = (unsigned long long*)d_ws;
        hipLaunchKernelGGL(bsh_precompute_gemm, dim3(56), dim3(512), 0, stream,
                           ar, ai, w, wc, bc, tb);
        hipLaunchKernelGGL(bsh_gemm, dim3(2304), dim3(512), 0, stream,
                           x, tb, out);
    } else {
        float* tbl = (float*)d_ws;
        hipLaunchKernelGGL(fb_precompute, dim3(1), dim3(512), 0, stream,
                           ar, ai, w, wc, bc, tbl);
        hipLaunchKernelGGL(fb_kernel, dim3(FB_NBLK), dim3(512), 0, stream,
                           x, tbl, out);
    }
}